// Round 9
// baseline (101.781 us; speedup 1.0000x reference)
//
#include <hip/hip_runtime.h>

// SqueezeSeg recurrent CRF, MI355X (gfx950).
// R9 = pre-softmax kernel (u0 packed [B,H,W,4] into d_ws, 1x work) +
//      fused 3-iteration halo-redundant kernel whose phase-0 is a single
//      coalesced float4 load per patch pixel (no exp / strided gather).
// Steps: double-buffered class-packed u in LDS, 1 barrier per step.
// g_ang == g_bi (theta=0.9 both) -> ang == bi_ang.
// compat = (1-I)*coef -> out[o] = coef*(sum_c v[c] - v[o]).

#define NCLASS 4
#define HH 64
#define WW 512
#define BB 16
#define TH 8
#define TW 64
#define UR (TH + 6)   // 14 rows : tile + 3 halo each side
#define UC (TW + 12)  // 76 cols : tile + 6 halo each side
#define PLANE (HH * WW)
#define NPIX (BB * HH * WW)   // 524288

// exp(-d2 / (2*0.9^2)) for d2 = 1,2,4,5
#define G1 0.53940412f
#define G2 0.29095687f
#define G4 0.08466190f
#define G5 0.04566227f

#define TAPS                                                                 \
    const int   DZ[14] = {-1,-1,-1,-1,-1,  0, 0, 0, 0,  1, 1, 1, 1, 1};      \
    const int   DA[14] = {-2,-1, 0, 1, 2, -2,-1, 1, 2, -2,-1, 0, 1, 2};      \
    const float GW[14] = {G5,G2,G1,G2,G5, G4,G1,G1,G4, G5,G2,G1,G2,G5};

__device__ __forceinline__ float4 softmax4(float4 v) {
    const float mx = fmaxf(fmaxf(v.x, v.y), fmaxf(v.z, v.w));
    const float e0 = __expf(v.x - mx);
    const float e1 = __expf(v.y - mx);
    const float e2 = __expf(v.z - mx);
    const float e3 = __expf(v.w - mx);
    const float inv = 1.0f / (e0 + e1 + e2 + e3);
    return make_float4(e0 * inv, e1 * inv, e2 * inv, e3 * inv);
}

// ---- pre-kernel: u0 = softmax(x, class dim), packed [B,H,W,4] ----
__global__ __launch_bounds__(256) void softmax_pack(
    const float* __restrict__ x, float4* __restrict__ up)
{
    const int i = blockIdx.x * 256 + threadIdx.x;   // i in [0, NPIX)
    const int b = i >> 15;                          // / (H*W) = 32768
    const int p = i & 32767;
    const float* px = x + (size_t)b * NCLASS * PLANE + p;
    up[i] = softmax4(make_float4(px[0], px[PLANE], px[2 * PLANE], px[3 * PLANE]));
}

// MR/MC: halo margin of the region this step computes.
// Reads u_src, writes softmaxed result to u_dst (FINAL: raw to global dst).
template <int MR, int MC, bool FINAL>
__device__ __forceinline__ void crf_step(
    const float4 (*__restrict__ u_src)[UC],
    float4 (*__restrict__ u_dst)[UC],
    const float (*__restrict__ m_lds)[UC],
    const float* __restrict__ filt, float* __restrict__ dst,
    int b, int h0, int w0, int tid)
{
    constexpr int RH = TH + 2 * MR;
    constexpr int RW = TW + 2 * MC;
    constexpr int NS = (RH * RW + 255) / 256;
    TAPS

#pragma unroll
    for (int j = 0; j < NS; ++j) {
        const int s = tid + 256 * j;
        if (s < RH * RW) {
            const int lr = s / RW;
            const int lc = s - lr * RW;
            const int gh = h0 + lr - MR;
            const int gw = w0 + lc - MC;
            const int ur = lr + (3 - MR);
            const int uc = lc + (6 - MC);
            const bool in = (gh >= 0) && (gh < HH) && (gw >= 0) && (gw < WW);
            float4 r = make_float4(0.f, 0.f, 0.f, 0.f);
            if (in) {
                float a0 = 0.f, a1 = 0.f, a2 = 0.f, a3 = 0.f;
                float c0 = 0.f, c1 = 0.f, c2 = 0.f, c3 = 0.f;
                const float mcen = m_lds[ur][uc];
                const float* fp = filt + ((size_t)b * 14 * HH + gh) * WW + gw;
#pragma unroll
                for (int k = 0; k < 14; ++k) {
                    const float  f  = fp[(size_t)k * PLANE];
                    const float  mn = m_lds[ur + DZ[k]][uc + DA[k]];
                    const float4 u  = u_src[ur + DZ[k]][uc + DA[k]];
                    const float  fm = f * mn;
                    const float  gk = GW[k];
                    a0 = fmaf(gk, u.x, a0);  c0 = fmaf(fm, u.x, c0);
                    a1 = fmaf(gk, u.y, a1);  c1 = fmaf(fm, u.y, c1);
                    a2 = fmaf(gk, u.z, a2);  c2 = fmaf(fm, u.z, c2);
                    a3 = fmaf(gk, u.w, a3);  c3 = fmaf(fm, u.w, c3);
                }
                const float b0 = c0 * mcen * a0;
                const float b1 = c1 * mcen * a1;
                const float b2 = c2 * mcen * a2;
                const float b3 = c3 * mcen * a3;
                const float sa = a0 + a1 + a2 + a3;
                const float sb = b0 + b1 + b2 + b3;
                const float4 ucen = u_src[ur][uc];
                r.x = ucen.x + 0.02f * (sa - a0) + 0.1f * (sb - b0);
                r.y = ucen.y + 0.02f * (sa - a1) + 0.1f * (sb - b1);
                r.z = ucen.z + 0.02f * (sa - a2) + 0.1f * (sb - b2);
                r.w = ucen.w + 0.02f * (sa - a3) + 0.1f * (sb - b3);
            }
            if (FINAL) {
                if (in) {
                    float* o = dst + ((size_t)b * NCLASS * HH + gh) * WW + gw;
                    o[0]         = r.x;
                    o[PLANE]     = r.y;
                    o[2 * PLANE] = r.z;
                    o[3 * PLANE] = r.w;
                }
            } else {
                u_dst[ur][uc] = in ? softmax4(r)
                                   : make_float4(0.f, 0.f, 0.f, 0.f);
            }
        }
    }
    if (!FINAL) __syncthreads();   // u_dst complete before next step reads it
}

__global__ __launch_bounds__(256, 4) void crf_fused(
    const float4* __restrict__ u0,   // [B,H,W,4] packed unary (pre-softmaxed)
    const float* __restrict__ filt,  // [B,1,14,H,W]
    const float* __restrict__ mask,  // [B,1,H,W]
    float* __restrict__ xout)        // [B,4,H,W]
{
    __shared__ float4 uA[UR][UC];    // 17.0 KB
    __shared__ float4 uB[UR][UC];    // 17.0 KB
    __shared__ float  m_lds[UR][UC]; //  4.3 KB  -> 38.3 KB, 4 blocks/CU

    const int b   = blockIdx.z;
    const int h0  = blockIdx.y * TH;
    const int w0  = blockIdx.x * TW;
    const int tid = threadIdx.x;

    // ---- phase 0: coalesced packed-u + mask loads over the 14x76 patch ----
    for (int idx = tid; idx < UR * UC; idx += 256) {
        const int lr = idx / UC;
        const int lc = idx - lr * UC;
        const int gh = h0 + lr - 3;
        const int gw = w0 + lc - 6;
        float4 u = make_float4(0.f, 0.f, 0.f, 0.f);
        float  m = 0.f;
        if (gh >= 0 && gh < HH && gw >= 0 && gw < WW) {
            const int p = ((b * HH) + gh) * WW + gw;
            u = u0[p];
            m = mask[p];
        }
        uA[lr][lc]    = u;
        m_lds[lr][lc] = m;
    }
    __syncthreads();

    crf_step<2, 4, false>(uA, uB, m_lds, filt, xout, b, h0, w0, tid);
    crf_step<1, 2, false>(uB, uA, m_lds, filt, xout, b, h0, w0, tid);
    crf_step<0, 0, true >(uA, uB, m_lds, filt, xout, b, h0, w0, tid);
}

extern "C" void kernel_launch(void* const* d_in, const int* in_sizes, int n_in,
                              void* d_out, int out_size, void* d_ws, size_t ws_size,
                              hipStream_t stream) {
    const float* x    = (const float*)d_in[0];  // [16,4,64,512]
    const float* filt = (const float*)d_in[1];  // [16,1,14,64,512]
    const float* msk  = (const float*)d_in[2];  // [16,1,64,512]
    float* out = (float*)d_out;
    float4* u0 = (float4*)d_ws;                 // 8.4 MB packed unary

    softmax_pack<<<NPIX / 256, 256, 0, stream>>>(x, u0);

    dim3 grid(WW / TW, HH / TH, BB);   // (8, 8, 16) = 1024 blocks = 4/CU
    dim3 block(256);
    crf_fused<<<grid, block, 0, stream>>>(u0, filt, msk, out);
}